// Round 8
// baseline (156.828 us; speedup 1.0000x reference)
//
#include <hip/hip_runtime.h>

// (T,B,N,D) = (32,16,2048,64)
constexpr int T = 32;
constexpr int NROWS = 16 * 2048;     // B*N
constexpr int D = 64;
constexpr long DYN = (long)T * NROWS * D;
constexpr long FIN = (long)NROWS * D;

typedef float f32x4  __attribute__((ext_vector_type(4)));
typedef short bf16x8 __attribute__((ext_vector_type(8)));

// f32 -> bf16 bits, round-to-nearest-even
__device__ __forceinline__ short f2b(float f) {
    union { float f; unsigned u; } v; v.f = f;
    unsigned r = (v.u + 0x7fffu + ((v.u >> 16) & 1u)) >> 16;
    return (short)r;
}
__device__ __forceinline__ float b2f(short b) {
    union { float f; unsigned u; } v; v.u = ((unsigned)(unsigned short)b) << 16;
    return v.f;
}

// Block = 128 threads = 2 waves, 16 rows/block, K=128 split across waves:
//   wv=0: k<64 (h columns), wv=1: k>=64 (s columns).
// R7 skeleton (2 barriers/step, zS/zH f32 handoff, full-line stores) plus:
//  - h state kept in LDS as bf16 in A-frag row layout -> H-wave A-frags are
//    two raw ds_read_b128, no per-step f32->bf16 chain. Rows are 128B so
//    b128 reads stay 16B-aligned; per-row epilogue access is 2 lanes/dword
//    (free). State quantization error ~2^-9, contracted by sigmoid' * t.
//  - s prefetch issued at step TOP into separate regs (sfB): full-step cover.
//  - thre s_loads hoisted to step top.

__global__ __launch_bounds__(128) void evo_kernel(
    const float* __restrict__ stat,   // [T][NROWS][D]
    const float* __restrict__ thre,   // [T][NROWS]
    const float* __restrict__ h0,     // [NROWS][D]
    const float* __restrict__ w1,     // [128][64]
    float* __restrict__ out)          // all_dyn | final | diffs
{
    __shared__ short hb16[16][64];    // 2KB bf16 h-state, A-frag layout
    __shared__ float zS[16][68];      // S-wave D frags
    __shared__ float zH[16][68];      // H-wave D frags

    const int lane = threadIdx.x & 63;
    const int wv   = __builtin_amdgcn_readfirstlane(threadIdx.x >> 6);
    const int row0 = blockIdx.x * 16;
    const int m = lane & 15;          // A row / B col
    const int q = lane >> 4;          // k-group

    // ---- B-frags: w1[64*wv + 32*kc + 8*q + j][m + 16*g], one-time ----
    bf16x8 B[2][4];
    {
        const float* wb = w1 + (long)(wv * 64) * 64;
#pragma unroll
        for (int kc = 0; kc < 2; ++kc)
#pragma unroll
            for (int g = 0; g < 4; ++g) {
                bf16x8 t;
#pragma unroll
                for (int j = 0; j < 8; ++j)
                    t[j] = f2b(wb[(kc * 32 + q * 8 + j) * 64 + m + 16 * g]);
                B[kc][g] = t;
            }
    }

    // ---- prologue: h0 rows [8wv,8wv+8) -> hb16 + all_dyn[0] ----
#pragma unroll
    for (int i2 = 0; i2 < 8; ++i2) {
        int i = wv * 8 + i2;
        float hv = h0[(long)(row0 + i) * D + lane];
        __builtin_nontemporal_store(hv, out + (long)(row0 + i) * D + lane);
        hb16[i][lane] = f2b(hv);
    }

    // ---- S-wave: load s(1) in A-frag layout ----
    f32x4 sfA[4], sfB[4];
    if (wv == 1) {
        const float* sp = stat + ((long)1 * NROWS + row0) * D;
#pragma unroll
        for (int kc = 0; kc < 2; ++kc)
#pragma unroll
            for (int hh = 0; hh < 2; ++hh)
                sfA[kc * 2 + hh] = __builtin_nontemporal_load(
                    (const f32x4*)(sp + m * 64 + kc * 32 + q * 8 + hh * 4));
    }
    __syncthreads();

#pragma unroll 1
    for (int tt = 1; tt < T; ++tt) {
        // ---- hoisted thre loads (wave-uniform -> s_load) ----
        const float* tp = thre + (long)tt * NROWS + row0 + wv * 8;
        float tg8[8];
#pragma unroll
        for (int i2 = 0; i2 < 8; ++i2) tg8[i2] = tp[i2];

        // ---- S-wave: issue NEXT step's loads first (max latency cover) ----
        if (wv == 1 && tt + 1 < T) {
            const float* sp = stat + ((long)(tt + 1) * NROWS + row0) * D;
#pragma unroll
            for (int kc = 0; kc < 2; ++kc)
#pragma unroll
                for (int hh = 0; hh < 2; ++hh)
                    sfB[kc * 2 + hh] = __builtin_nontemporal_load(
                        (const f32x4*)(sp + m * 64 + kc * 32 + q * 8 + hh * 4));
        }

        // ---- A-frags ----
        bf16x8 A[2];
        if (wv == 0) {
#pragma unroll
            for (int kc = 0; kc < 2; ++kc)
                A[kc] = *(const bf16x8*)&hb16[m][kc * 32 + q * 8];   // raw b128
        } else {
#pragma unroll
            for (int kc = 0; kc < 2; ++kc) {
                bf16x8 a;
#pragma unroll
                for (int e = 0; e < 4; ++e) { a[e] = f2b(sfA[kc * 2][e]); a[4 + e] = f2b(sfA[kc * 2 + 1][e]); }
                A[kc] = a;
            }
        }

        // ---- 8 MFMA ----
        f32x4 dacc[4] = {{0.f,0.f,0.f,0.f},{0.f,0.f,0.f,0.f},{0.f,0.f,0.f,0.f},{0.f,0.f,0.f,0.f}};
#pragma unroll
        for (int g = 0; g < 4; ++g)
#pragma unroll
            for (int kc = 0; kc < 2; ++kc)
                dacc[g] = __builtin_amdgcn_mfma_f32_16x16x32_bf16(A[kc], B[kc][g], dacc[g], 0, 0, 0);

        // ---- D -> z-buffer (row = 4q+rr, col = m+16g) ----
        float (*zbuf)[68] = wv ? zS : zH;
#pragma unroll
        for (int g = 0; g < 4; ++g)
#pragma unroll
            for (int rr = 0; rr < 4; ++rr)
                zbuf[q * 4 + rr][m + 16 * g] = dacc[g][rr];

        __syncthreads();   // z complete

        // ---- epilogue: rows [8wv, 8wv+8), lane = col ----
        {
            float* od = out + ((long)tt * NROWS + row0) * D + lane;
            float* dd = out + DYN + FIN + ((long)(tt - 1) * NROWS + row0) * D + lane;
#pragma unroll
            for (int i2 = 0; i2 < 8; ++i2) {
                int i  = wv * 8 + i2;
                float z  = zS[i][lane] + zH[i][lane];
                float hp = b2f(hb16[i][lane]);
                float v  = fmaf(tg8[i2], z - hp, hp);    // z*t + h*(1-t)
                float hn = 1.0f / (1.0f + __expf(-v));
                float df = hn - hp;
                hb16[i][lane] = f2b(hn);                 // state for next step
                __builtin_nontemporal_store(hn, od + (long)i * D);
                __builtin_nontemporal_store(df, dd + (long)i * D);
                if (tt == T - 1)
                    __builtin_nontemporal_store(hn, out + DYN + (long)(row0 + i) * D + lane);
            }
        }
        __syncthreads();   // h/z consumed before next step overwrites

        if (wv == 1 && tt + 1 < T) {
#pragma unroll
            for (int c = 0; c < 4; ++c) sfA[c] = sfB[c];
        }
    }
}

extern "C" void kernel_launch(void* const* d_in, const int* in_sizes, int n_in,
                              void* d_out, int out_size, void* d_ws, size_t ws_size,
                              hipStream_t stream) {
    const float* stat = (const float*)d_in[0];
    const float* thre = (const float*)d_in[1];
    const float* h0   = (const float*)d_in[2];
    const float* w1   = (const float*)d_in[3];
    float* out = (float*)d_out;

    dim3 grid(NROWS / 16);   // 2048 blocks -> 8 blocks/CU
    dim3 block(128);
    evo_kernel<<<grid, block, 0, stream>>>(stat, thre, h0, w1, out);
}

// Round 9
// 156.737 us; speedup vs baseline: 1.0006x; 1.0006x over previous
//
#include <hip/hip_runtime.h>

// (T,B,N,D) = (32,16,2048,64)
constexpr int T = 32;
constexpr int NROWS = 16 * 2048;     // B*N
constexpr int D = 64;
constexpr long DYN = (long)T * NROWS * D;
constexpr long FIN = (long)NROWS * D;

typedef float f32x4  __attribute__((ext_vector_type(4)));
typedef short bf16x8 __attribute__((ext_vector_type(8)));

// f32 -> bf16 bits, round-to-nearest-even
__device__ __forceinline__ short f2b(float f) {
    union { float f; unsigned u; } v; v.f = f;
    unsigned r = (v.u + 0x7fffu + ((v.u >> 16) & 1u)) >> 16;
    return (short)r;
}
__device__ __forceinline__ float b2f(short b) {
    union { float f; unsigned u; } v; v.u = ((unsigned)(unsigned short)b) << 16;
    return v.f;
}

// LGKM-only workgroup barrier: LDS handoff needs lgkmcnt(0) + s_barrier, but
// NOT vmcnt(0) -- __syncthreads() drains all outstanding global STORES (HBM
// ack round-trip) twice per step, which R8 showed is the residual ~20%
// overhead over the memory roofline. Global stores here are never re-read
// by the device, so leaving them in flight across the barrier is safe.
__device__ __forceinline__ void lds_barrier() {
    asm volatile("s_waitcnt lgkmcnt(0)\n\ts_barrier" ::: "memory");
}

// Block = 128 threads = 2 waves, 16 rows/block, K=128 split across waves:
//   wv=0: k<64 (h columns), wv=1: k>=64 (s columns).
// Each wave: its w1-half as 8 bf16 B-frags (32 VGPRs); 8 MFMA/step; D-frags
// through small LDS z-buffers; h state in LDS as bf16 in A-frag row layout
// (raw ds_read_b128 for H A-frags); s loaded per-lane from global directly
// in A-frag layout (full 128B lines, no LDS). Epilogue splits rows across
// waves, lane = col -> full 256B-line stores.

__global__ __launch_bounds__(128) void evo_kernel(
    const float* __restrict__ stat,   // [T][NROWS][D]
    const float* __restrict__ thre,   // [T][NROWS]
    const float* __restrict__ h0,     // [NROWS][D]
    const float* __restrict__ w1,     // [128][64]
    float* __restrict__ out)          // all_dyn | final | diffs
{
    __shared__ short hb16[16][64];    // 2KB bf16 h-state, A-frag layout
    __shared__ float zS[16][68];      // S-wave D frags
    __shared__ float zH[16][68];      // H-wave D frags

    const int lane = threadIdx.x & 63;
    const int wv   = __builtin_amdgcn_readfirstlane(threadIdx.x >> 6);
    const int row0 = blockIdx.x * 16;
    const int m = lane & 15;          // A row / B col
    const int q = lane >> 4;          // k-group

    // ---- B-frags: w1[64*wv + 32*kc + 8*q + j][m + 16*g], one-time ----
    bf16x8 B[2][4];
    {
        const float* wb = w1 + (long)(wv * 64) * 64;
#pragma unroll
        for (int kc = 0; kc < 2; ++kc)
#pragma unroll
            for (int g = 0; g < 4; ++g) {
                bf16x8 t;
#pragma unroll
                for (int j = 0; j < 8; ++j)
                    t[j] = f2b(wb[(kc * 32 + q * 8 + j) * 64 + m + 16 * g]);
                B[kc][g] = t;
            }
    }

    // ---- prologue: h0 rows [8wv,8wv+8) -> hb16 + all_dyn[0] ----
#pragma unroll
    for (int i2 = 0; i2 < 8; ++i2) {
        int i = wv * 8 + i2;
        float hv = h0[(long)(row0 + i) * D + lane];
        __builtin_nontemporal_store(hv, out + (long)(row0 + i) * D + lane);
        hb16[i][lane] = f2b(hv);
    }

    // ---- S-wave: load s(1) in A-frag layout ----
    f32x4 sfA[4], sfB[4];
    if (wv == 1) {
        const float* sp = stat + ((long)1 * NROWS + row0) * D;
#pragma unroll
        for (int kc = 0; kc < 2; ++kc)
#pragma unroll
            for (int hh = 0; hh < 2; ++hh)
                sfA[kc * 2 + hh] = __builtin_nontemporal_load(
                    (const f32x4*)(sp + m * 64 + kc * 32 + q * 8 + hh * 4));
    }
    lds_barrier();

#pragma unroll 1
    for (int tt = 1; tt < T; ++tt) {
        // ---- hoisted thre loads (wave-uniform -> s_load) ----
        const float* tp = thre + (long)tt * NROWS + row0 + wv * 8;
        float tg8[8];
#pragma unroll
        for (int i2 = 0; i2 < 8; ++i2) tg8[i2] = tp[i2];

        // ---- S-wave: issue NEXT step's loads first (max latency cover) ----
        if (wv == 1 && tt + 1 < T) {
            const float* sp = stat + ((long)(tt + 1) * NROWS + row0) * D;
#pragma unroll
            for (int kc = 0; kc < 2; ++kc)
#pragma unroll
                for (int hh = 0; hh < 2; ++hh)
                    sfB[kc * 2 + hh] = __builtin_nontemporal_load(
                        (const f32x4*)(sp + m * 64 + kc * 32 + q * 8 + hh * 4));
        }

        // ---- A-frags ----
        bf16x8 A[2];
        if (wv == 0) {
#pragma unroll
            for (int kc = 0; kc < 2; ++kc)
                A[kc] = *(const bf16x8*)&hb16[m][kc * 32 + q * 8];   // raw b128
        } else {
#pragma unroll
            for (int kc = 0; kc < 2; ++kc) {
                bf16x8 a;
#pragma unroll
                for (int e = 0; e < 4; ++e) { a[e] = f2b(sfA[kc * 2][e]); a[4 + e] = f2b(sfA[kc * 2 + 1][e]); }
                A[kc] = a;
            }
        }

        // ---- 8 MFMA ----
        f32x4 dacc[4] = {{0.f,0.f,0.f,0.f},{0.f,0.f,0.f,0.f},{0.f,0.f,0.f,0.f},{0.f,0.f,0.f,0.f}};
#pragma unroll
        for (int g = 0; g < 4; ++g)
#pragma unroll
            for (int kc = 0; kc < 2; ++kc)
                dacc[g] = __builtin_amdgcn_mfma_f32_16x16x32_bf16(A[kc], B[kc][g], dacc[g], 0, 0, 0);

        // ---- D -> z-buffer (row = 4q+rr, col = m+16g) ----
        float (*zbuf)[68] = wv ? zS : zH;
#pragma unroll
        for (int g = 0; g < 4; ++g)
#pragma unroll
            for (int rr = 0; rr < 4; ++rr)
                zbuf[q * 4 + rr][m + 16 * g] = dacc[g][rr];

        lds_barrier();   // z complete (LDS only; stores stay in flight)

        // ---- epilogue: rows [8wv, 8wv+8), lane = col ----
        {
            float* od = out + ((long)tt * NROWS + row0) * D + lane;
            float* dd = out + DYN + FIN + ((long)(tt - 1) * NROWS + row0) * D + lane;
#pragma unroll
            for (int i2 = 0; i2 < 8; ++i2) {
                int i  = wv * 8 + i2;
                float z  = zS[i][lane] + zH[i][lane];
                float hp = b2f(hb16[i][lane]);
                float v  = fmaf(tg8[i2], z - hp, hp);    // z*t + h*(1-t)
                float hn = 1.0f / (1.0f + __expf(-v));
                float df = hn - hp;
                hb16[i][lane] = f2b(hn);                 // state for next step
                __builtin_nontemporal_store(hn, od + (long)i * D);
                __builtin_nontemporal_store(df, dd + (long)i * D);
                if (tt == T - 1)
                    __builtin_nontemporal_store(hn, out + DYN + (long)(row0 + i) * D + lane);
            }
        }
        lds_barrier();   // h/z consumed before next step overwrites

        if (wv == 1 && tt + 1 < T) {
#pragma unroll
            for (int c = 0; c < 4; ++c) sfA[c] = sfB[c];
        }
    }
}

extern "C" void kernel_launch(void* const* d_in, const int* in_sizes, int n_in,
                              void* d_out, int out_size, void* d_ws, size_t ws_size,
                              hipStream_t stream) {
    const float* stat = (const float*)d_in[0];
    const float* thre = (const float*)d_in[1];
    const float* h0   = (const float*)d_in[2];
    const float* w1   = (const float*)d_in[3];
    float* out = (float*)d_out;

    dim3 grid(NROWS / 16);   // 2048 blocks -> 8 blocks/CU
    dim3 block(128);
    evo_kernel<<<grid, block, 0, stream>>>(stat, thre, h0, w1, out);
}

// Round 10
// 135.243 us; speedup vs baseline: 1.1596x; 1.1589x over previous
//
#include <hip/hip_runtime.h>

// (T,B,N,D) = (32,16,2048,64)
constexpr int T = 32;
constexpr int NROWS = 16 * 2048;     // B*N
constexpr int D = 64;
constexpr long DYN = (long)T * NROWS * D;
constexpr long FIN = (long)NROWS * D;

typedef float f32x4  __attribute__((ext_vector_type(4)));
typedef short bf16x8 __attribute__((ext_vector_type(8)));

__device__ __forceinline__ short f2b(float f) {
    union { float f; unsigned u; } v; v.f = f;
    unsigned r = (v.u + 0x7fffu + ((v.u >> 16) & 1u)) >> 16;
    return (short)r;
}
__device__ __forceinline__ float b2f(short b) {
    union { float f; unsigned u; } v; v.u = ((unsigned)(unsigned short)b) << 16;
    return v.f;
}
__device__ __forceinline__ void gload16(const float* g, float* l) {
    __builtin_amdgcn_global_load_lds(
        (const __attribute__((address_space(1))) unsigned int*)(unsigned long long)(const void*)g,
        (__attribute__((address_space(3))) unsigned int*)(unsigned long long)(void*)l,
        16, 0, 0);
}

// ONE autonomous wave per block, 16 rows, full K=128. Zero barriers (all LDS
// handoffs are intra-wave; compiler lgkmcnt orders them). 16 bf16 B-frags in
// 64 VGPRs; 16x mfma_f32_16x16x32_bf16 per step. s staged global->LDS via
// global_load_lds one step ahead; counted s_waitcnt vmcnt(32) (= #stores
// issued since the prefetch) so the in-flight prefetch is never drained.
// h state bf16 in LDS. Both sb and hb16 are XOR-swizzled (byte ^= (row&7)<<4)
// so A-frag ds_read_b128 spreads banks; sb's swizzle is applied by
// PRE-SWIZZLING the global source (global_load_lds writes LDS linearly).
// R7-R9 lesson: 2-wave split left one wave idling at each barrier; this
// removes barriers, z-sum, and partner imbalance entirely.

__global__ __launch_bounds__(64) void evo_kernel(
    const float* __restrict__ stat,   // [T][NROWS][D]
    const float* __restrict__ thre,   // [T][NROWS]
    const float* __restrict__ h0,     // [NROWS][D]
    const float* __restrict__ w1,     // [128][64]
    float* __restrict__ out)          // all_dyn | final | diffs
{
    __shared__ float sb[2][16][64];   // 8 KB  s tiles (swizzled, dbuf)
    __shared__ short hb16[16][64];    // 2 KB  bf16 h state (swizzled)
    __shared__ float zb[16][68];      // 4.25 KB z transpose (padded)

    const int lane = threadIdx.x;     // 0..63
    const int row0 = blockIdx.x * 16;
    const int m = lane & 15;          // A row / B col
    const int q = lane >> 4;          // k-group

    // swizzled accessors
    auto hb_addr = [&](int row, int colb) -> char* {   // colb = byte col in 128B row
        return (char*)hb16 + ((row * 128 + colb) ^ ((row & 7) << 4));
    };
    auto sb_quad = [&](int buf, int row, int c0) -> const f32x4* {
        int byte = ((row * 64 + c0) * 4) ^ ((row & 7) << 4);
        return (const f32x4*)((const char*)&sb[buf][0][0] + byte);
    };
    auto stage_s = [&](int t2, int buf) {              // pre-swizzled global -> linear LDS
        const float* sp = stat + ((long)t2 * NROWS + row0) * D;
        float* lb = &sb[buf][0][0];
#pragma unroll
        for (int c = 0; c < 4; ++c) {
            int f  = c * 1024 + lane * 16;             // dest byte in 4KB tile
            int mm = f >> 8;
            int gb = (f & ~255) | ((f & 255) ^ ((mm & 7) << 4));
            gload16(sp + (gb >> 2), lb + c * 256);
        }
    };

    // ---- B-frags: w1[kc*32 + q*8 + j][m + 16g], one-time, 64 VGPRs ----
    bf16x8 B[4][4];
#pragma unroll
    for (int kc = 0; kc < 4; ++kc)
#pragma unroll
        for (int g = 0; g < 4; ++g) {
            bf16x8 t;
#pragma unroll
            for (int j = 0; j < 8; ++j)
                t[j] = f2b(w1[(kc * 32 + q * 8 + j) * 64 + m + 16 * g]);
            B[kc][g] = t;
        }

    // ---- prologue: issue s(1) prefetch FIRST, then h0 ----
    stage_s(1, 1);
#pragma unroll
    for (int i = 0; i < 16; ++i) {
        float hv = h0[(long)(row0 + i) * D + lane];
        __builtin_nontemporal_store(hv, out + (long)(row0 + i) * D + lane);
        *(short*)hb_addr(i, lane * 2) = f2b(hv);
    }
    asm volatile("s_waitcnt vmcnt(0)" ::: "memory");   // one-time drain: sb[1] ready

#pragma unroll 1
    for (int tt = 1; tt < T; ++tt) {
        const int p = tt & 1;

        // sb[p]'s 4 gloads were issued last iter; exactly 32 stores followed.
        asm volatile("s_waitcnt vmcnt(32)" ::: "memory");

        if (tt + 1 < T) stage_s(tt + 1, p ^ 1);

        // thre (wave-uniform -> s_load)
        const float* tp = thre + (long)tt * NROWS + row0;
        float tg[16];
#pragma unroll
        for (int i = 0; i < 16; ++i) tg[i] = tp[i];

        // ---- 16 MFMA: kc outer (A built once, 4 g's inner) ----
        f32x4 dacc[4] = {{0.f,0.f,0.f,0.f},{0.f,0.f,0.f,0.f},{0.f,0.f,0.f,0.f},{0.f,0.f,0.f,0.f}};
#pragma unroll
        for (int kc = 0; kc < 4; ++kc) {
            bf16x8 A;
            if (kc < 2) {
                A = *(const bf16x8*)hb_addr(m, kc * 64 + q * 16);   // raw b128 bf16
            } else {
                f32x4 lo = *sb_quad(p, m, (kc - 2) * 32 + q * 8);
                f32x4 hi = *sb_quad(p, m, (kc - 2) * 32 + q * 8 + 4);
#pragma unroll
                for (int e = 0; e < 4; ++e) { A[e] = f2b(lo[e]); A[4 + e] = f2b(hi[e]); }
            }
#pragma unroll
            for (int g = 0; g < 4; ++g)
                dacc[g] = __builtin_amdgcn_mfma_f32_16x16x32_bf16(A, B[kc][g], dacc[g], 0, 0, 0);
        }

        // ---- z transpose through LDS (row = 4q+rr, col = m+16g) ----
#pragma unroll
        for (int g = 0; g < 4; ++g)
#pragma unroll
            for (int rr = 0; rr < 4; ++rr)
                zb[q * 4 + rr][m + 16 * g] = dacc[g][rr];

        // ---- epilogue: 16 rows, lane = col; exactly 32 global stores ----
        float* od = out + ((long)tt * NROWS + row0) * D + lane;
        float* dd = out + DYN + FIN + ((long)(tt - 1) * NROWS + row0) * D + lane;
#pragma unroll
        for (int i = 0; i < 16; ++i) {
            float z  = zb[i][lane];
            float hp = b2f(*(const short*)hb_addr(i, lane * 2));
            float v  = fmaf(tg[i], z - hp, hp);        // z*t + h*(1-t)
            float hn = 1.0f / (1.0f + __expf(-v));
            float df = hn - hp;
            *(short*)hb_addr(i, lane * 2) = f2b(hn);   // state for next step
            __builtin_nontemporal_store(hn, od + (long)i * D);
            __builtin_nontemporal_store(df, dd + (long)i * D);
        }
        if (tt == T - 1) {
#pragma unroll
            for (int i = 0; i < 16; ++i) {
                float hn = b2f(*(const short*)hb_addr(i, lane * 2));
                __builtin_nontemporal_store(hn, out + DYN + (long)(row0 + i) * D + lane);
            }
        }
    }
}

extern "C" void kernel_launch(void* const* d_in, const int* in_sizes, int n_in,
                              void* d_out, int out_size, void* d_ws, size_t ws_size,
                              hipStream_t stream) {
    const float* stat = (const float*)d_in[0];
    const float* thre = (const float*)d_in[1];
    const float* h0   = (const float*)d_in[2];
    const float* w1   = (const float*)d_in[3];
    float* out = (float*)d_out;

    dim3 grid(NROWS / 16);   // 2048 single-wave blocks -> 8/CU
    dim3 block(64);
    evo_kernel<<<grid, block, 0, stream>>>(stat, thre, h0, w1, out);
}